// Round 3
// baseline (336.890 us; speedup 1.0000x reference)
//
#include <hip/hip_runtime.h>

// B-spline 3D field, 2M points, 128^3 x 3 f32 grid.
// Round 3:
//  - sort side: global hist (LDS-aggregated) -> single-block scan ->
//    scatter via global atomicAdd on 64B-padded bin cursors. Removes the
//    serially-dependent totals/fixup column walks (~90 us in round 2).
//  - eval side: LDS brick stored as z-windows W[row][lzb][comp], each
//    float4 = 4 consecutive z-values of one component -> 3 aligned
//    ds_read_b128 per (l,m) row (was 4), all 16 bytes useful.

#define NBINS 4096        // 16x16x16 bins of 8^3 cells
#define CUR_STRIDE 16     // u32 stride between cursors (64B, channel spread)
#define NW (121 * 8 * 3)  // z-window float4 count per brick

__device__ __forceinline__ void bspline_w(float u, float& w0, float& w1,
                                          float& w2, float& w3) {
    const float u2 = u * u;
    const float u3 = u2 * u;
    const float t  = 1.0f - u;
    w0 = t * t * t * (1.0f / 6.0f);
    w1 = (3.0f * u3 - 6.0f * u2 + 4.0f) * (1.0f / 6.0f);
    w2 = (-3.0f * u3 + 3.0f * u2 + 3.0f * u + 1.0f) * (1.0f / 6.0f);
    w3 = u3 * (1.0f / 6.0f);
}

__device__ __forceinline__ void cell_ids(float x, float y, float z,
                                         int& ix, int& iy, int& iz) {
    const float dx = 2.0f / 125.0f;
    const float ox = -1.0f - dx;
    ix = (int)floorf((x - ox - dx) / dx);
    iy = (int)floorf((y - ox - dx) / dx);
    iz = (int)floorf((z - ox - dx) / dx);
}

__device__ __forceinline__ int point_bin(float x, float y, float z) {
    int ix, iy, iz;
    cell_ids(x, y, z, ix, iy, iz);
    const int bx = min(max(ix, 0), 127) >> 3;
    const int by = min(max(iy, 0), 127) >> 3;
    const int bz = min(max(iz, 0), 127) >> 3;
    return (bx << 8) | (by << 4) | bz;
}

// ---- pass A: global histogram (LDS-aggregated) ----
__global__ __launch_bounds__(256) void hist_kernel(
    const float* __restrict__ xs, const float* __restrict__ ys,
    const float* __restrict__ zs, unsigned* __restrict__ hist, int n) {
    __shared__ unsigned h[NBINS];
    for (int j = threadIdx.x; j < NBINS; j += 256) h[j] = 0;
    __syncthreads();
    const int stride = gridDim.x * 256;
    for (int i = blockIdx.x * 256 + threadIdx.x; i < n; i += stride)
        atomicAdd(&h[point_bin(xs[i], ys[i], zs[i])], 1u);
    __syncthreads();
    for (int j = threadIdx.x; j < NBINS; j += 256)
        if (h[j]) atomicAdd(&hist[j], h[j]);
}

// ---- pass B: exclusive scan of hist -> binbase, init cursors ----
__global__ __launch_bounds__(1024) void scan_kernel(
    const unsigned* __restrict__ hist, unsigned* __restrict__ binbase,
    unsigned* __restrict__ cursor) {
    __shared__ unsigned sdata[1024];
    const int t = threadIdx.x;
    const unsigned v0 = hist[4 * t + 0];
    const unsigned v1 = hist[4 * t + 1];
    const unsigned v2 = hist[4 * t + 2];
    const unsigned v3 = hist[4 * t + 3];
    sdata[t] = v0 + v1 + v2 + v3;
    __syncthreads();
    for (int off = 1; off < 1024; off <<= 1) {
        unsigned x = (t >= off) ? sdata[t - off] : 0u;
        __syncthreads();
        sdata[t] += x;
        __syncthreads();
    }
    const unsigned ex = (t > 0) ? sdata[t - 1] : 0u;
    const unsigned b0 = ex;
    const unsigned b1 = ex + v0;
    const unsigned b2 = b1 + v1;
    const unsigned b3 = b2 + v2;
    binbase[4 * t + 0] = b0;
    binbase[4 * t + 1] = b1;
    binbase[4 * t + 2] = b2;
    binbase[4 * t + 3] = b3;
    cursor[(4 * t + 0) * CUR_STRIDE] = b0;
    cursor[(4 * t + 1) * CUR_STRIDE] = b1;
    cursor[(4 * t + 2) * CUR_STRIDE] = b2;
    cursor[(4 * t + 3) * CUR_STRIDE] = b3;
}

// ---- pass C: scatter records via global atomic cursors ----
__global__ __launch_bounds__(256) void scatter_kernel(
    const float* __restrict__ xs, const float* __restrict__ ys,
    const float* __restrict__ zs, unsigned* __restrict__ cursor,
    float4* __restrict__ rec, int n) {
    const int stride = gridDim.x * 256;
    for (int i = blockIdx.x * 256 + threadIdx.x; i < n; i += stride) {
        const float x = xs[i], y = ys[i], z = zs[i];
        const int bin = point_bin(x, y, z);
        const unsigned p = atomicAdd(&cursor[bin * CUR_STRIDE], 1u);
        rec[p] = make_float4(x, y, z, __int_as_float(i));
    }
}

// ---- pass D: evaluate, one block per bin, z-window brick in LDS ----
__global__ __launch_bounds__(256) void eval_kernel(
    const float4* __restrict__ rec, const unsigned* __restrict__ binbase,
    const unsigned* __restrict__ hist, const float* __restrict__ phi,
    float* __restrict__ out) {
    const int bin = blockIdx.x;
    const unsigned cnt = hist[bin];
    if (cnt == 0) return;
    const unsigned start = binbase[bin];

    const int gx0 = ((bin >> 8) & 15) << 3;
    const int gy0 = ((bin >> 4) & 15) << 3;
    const int gz0 = (bin & 15) << 3;

    // W[row][s][c]: float4 = component c at z = gz0+s .. gz0+s+3 (clamped),
    // row = lx*11+ly. 121*8*3 float4 = 46.5 KB.
    __shared__ float4 W[NW];
    for (int p = threadIdx.x; p < NW; p += 256) {
        const int c   = p % 3;
        const int t   = p / 3;
        const int s   = t & 7;
        const int row = t >> 3;
        const int lx  = row / 11;
        const int ly  = row - lx * 11;
        const int gx = min(gx0 + lx, 127);
        const int gy = min(gy0 + ly, 127);
        const float* src = phi + (size_t)((gx * 128 + gy) * 128) * 3 + c;
        float4 v;
        v.x = src[3 * min(gz0 + s + 0, 127)];
        v.y = src[3 * min(gz0 + s + 1, 127)];
        v.z = src[3 * min(gz0 + s + 2, 127)];
        v.w = src[3 * min(gz0 + s + 3, 127)];
        W[p] = v;
    }
    __syncthreads();

    const float dx = 2.0f / 125.0f;
    const float ox = -1.0f - dx;

    for (unsigned k = start + threadIdx.x; k < start + cnt; k += 256) {
        const float4 r4 = rec[k];
        const int idx = __float_as_int(r4.w);

        const float U = (r4.x - ox - dx) / dx;
        const float V = (r4.y - ox - dx) / dx;
        const float Z = (r4.z - ox - dx) / dx;
        const float fu = floorf(U), fv = floorf(V), fw = floorf(Z);
        const int ix = (int)fu, iy = (int)fv, iz = (int)fw;
        const float u = U - fu, v = V - fv, w = Z - fw;

        float wu[4], wv[4], wz[4];
        bspline_w(u, wu[0], wu[1], wu[2], wu[3]);
        bspline_w(v, wv[0], wv[1], wv[2], wv[3]);
        bspline_w(w, wz[0], wz[1], wz[2], wz[3]);

        // z clamp via weight shift
        int izb = iz < 0 ? 0 : iz;
        const bool sh = izb > 124;
        if (sh) izb = 124;
        const float zw0 = sh ? 0.0f : wz[0];
        const float zw1 = sh ? wz[0] : wz[1];
        const float zw2 = sh ? wz[1] : wz[2];
        const float zw3 = sh ? (wz[2] + wz[3]) : wz[3];
        const int lzb = izb - gz0;  // [0,7]

        int lxi[4], lyi[4];
#pragma unroll
        for (int l = 0; l < 4; ++l) {
            lxi[l] = min(max(ix + l, 0), 127) - gx0;
            lyi[l] = min(max(iy + l, 0), 127) - gy0;
        }

        float acc0 = 0.0f, acc1 = 0.0f, acc2 = 0.0f;
#pragma unroll
        for (int l = 0; l < 4; ++l) {
            const int rowx = lxi[l] * 11;
#pragma unroll
            for (int m = 0; m < 4; ++m) {
                const int base = ((rowx + lyi[m]) * 8 + lzb) * 3;
                const float4 a = W[base + 0];  // comp0 z..z+3
                const float4 b = W[base + 1];  // comp1
                const float4 c = W[base + 2];  // comp2
                const float wm = wu[l] * wv[m];
                const float c0 = wm * zw0;
                const float c1 = wm * zw1;
                const float c2 = wm * zw2;
                const float c3 = wm * zw3;
                acc0 = fmaf(c0, a.x, acc0);
                acc0 = fmaf(c1, a.y, acc0);
                acc0 = fmaf(c2, a.z, acc0);
                acc0 = fmaf(c3, a.w, acc0);
                acc1 = fmaf(c0, b.x, acc1);
                acc1 = fmaf(c1, b.y, acc1);
                acc1 = fmaf(c2, b.z, acc1);
                acc1 = fmaf(c3, b.w, acc1);
                acc2 = fmaf(c0, c.x, acc2);
                acc2 = fmaf(c1, c.y, acc2);
                acc2 = fmaf(c2, c.z, acc2);
                acc2 = fmaf(c3, c.w, acc2);
            }
        }
        float* o = out + 3 * (size_t)idx;
        o[0] = acc0;
        o[1] = acc1;
        o[2] = acc2;
    }
}

// ---- fallback: round-1 direct kernel ----
__global__ __launch_bounds__(256) void bspline3d_direct(
    const float* __restrict__ xs, const float* __restrict__ ys,
    const float* __restrict__ zs, const float* __restrict__ phi,
    float* __restrict__ out, int n) {
    const int i = blockIdx.x * blockDim.x + threadIdx.x;
    if (i >= n) return;
    const float dx = 2.0f / 125.0f;
    const float ox = -1.0f - dx;
    float u = (xs[i] - ox - dx) / dx;
    float v = (ys[i] - ox - dx) / dx;
    float w = (zs[i] - ox - dx) / dx;
    const float fu = floorf(u), fv = floorf(v), fw = floorf(w);
    const int ix = (int)fu, iy = (int)fv, iz = (int)fw;
    u -= fu; v -= fv; w -= fw;
    float wu[4], wv[4], wz[4];
    bspline_w(u, wu[0], wu[1], wu[2], wu[3]);
    bspline_w(v, wv[0], wv[1], wv[2], wv[3]);
    bspline_w(w, wz[0], wz[1], wz[2], wz[3]);
    int izb = iz < 0 ? 0 : iz;
    const bool sh = izb > 124;
    if (sh) izb = 124;
    const float zw0 = sh ? 0.0f : wz[0];
    const float zw1 = sh ? wz[0] : wz[1];
    const float zw2 = sh ? wz[1] : wz[2];
    const float zw3 = sh ? (wz[2] + wz[3]) : wz[3];
    int xi[4], yi[4];
#pragma unroll
    for (int l = 0; l < 4; ++l) {
        xi[l] = min(max(ix + l, 0), 127);
        yi[l] = min(max(iy + l, 0), 127);
    }
    const float* pz = phi + izb * 3;
    float acc0 = 0.0f, acc1 = 0.0f, acc2 = 0.0f;
#pragma unroll
    for (int l = 0; l < 4; ++l) {
        const int rowx = xi[l] << 7;
#pragma unroll
        for (int m = 0; m < 4; ++m) {
            const float* p = pz + (rowx + yi[m]) * 384;
            const float4 a = *reinterpret_cast<const float4*>(p);
            const float4 b = *reinterpret_cast<const float4*>(p + 4);
            const float4 c = *reinterpret_cast<const float4*>(p + 8);
            const float wm = wu[l] * wv[m];
            const float c0 = wm * zw0, c1 = wm * zw1, c2 = wm * zw2, c3 = wm * zw3;
            acc0 = fmaf(c0, a.x, acc0); acc1 = fmaf(c0, a.y, acc1); acc2 = fmaf(c0, a.z, acc2);
            acc0 = fmaf(c1, a.w, acc0); acc1 = fmaf(c1, b.x, acc1); acc2 = fmaf(c1, b.y, acc2);
            acc0 = fmaf(c2, b.z, acc0); acc1 = fmaf(c2, b.w, acc1); acc2 = fmaf(c2, c.x, acc2);
            acc0 = fmaf(c3, c.y, acc0); acc1 = fmaf(c3, c.z, acc1); acc2 = fmaf(c3, c.w, acc2);
        }
    }
    float* o = out + 3 * (size_t)i;
    o[0] = acc0; o[1] = acc1; o[2] = acc2;
}

extern "C" void kernel_launch(void* const* d_in, const int* in_sizes, int n_in,
                              void* d_out, int out_size, void* d_ws,
                              size_t ws_size, hipStream_t stream) {
    const float* xs  = (const float*)d_in[0];
    const float* ys  = (const float*)d_in[1];
    const float* zs  = (const float*)d_in[2];
    const float* phi = (const float*)d_in[3];
    float* out = (float*)d_out;
    const int n = in_sizes[0];

    // ws layout
    const size_t hist_off   = 0;                              // u32[4096]
    const size_t base_off   = hist_off + NBINS * 4;           // u32[4096]
    const size_t cursor_off = base_off + NBINS * 4;           // u32[4096*16]
    const size_t rec_off    = cursor_off + (size_t)NBINS * CUR_STRIDE * 4;
    const size_t need = rec_off + (size_t)n * 16;

    if (ws_size < need) {
        bspline3d_direct<<<(n + 255) / 256, 256, 0, stream>>>(xs, ys, zs, phi,
                                                              out, n);
        return;
    }

    unsigned* hist    = (unsigned*)((char*)d_ws + hist_off);
    unsigned* binbase = (unsigned*)((char*)d_ws + base_off);
    unsigned* cursor  = (unsigned*)((char*)d_ws + cursor_off);
    float4*   rec     = (float4*)((char*)d_ws + rec_off);

    hipMemsetAsync(hist, 0, NBINS * 4, stream);
    hist_kernel<<<512, 256, 0, stream>>>(xs, ys, zs, hist, n);
    scan_kernel<<<1, 1024, 0, stream>>>(hist, binbase, cursor);
    scatter_kernel<<<512, 256, 0, stream>>>(xs, ys, zs, cursor, rec, n);
    eval_kernel<<<NBINS, 256, 0, stream>>>(rec, binbase, hist, phi, out);
}

// Round 4
// 224.692 us; speedup vs baseline: 1.4993x; 1.4993x over previous
//
#include <hip/hip_runtime.h>

// B-spline 3D field, 2M points, 128^3 x 3 f32 grid.
// Round 4:
//  - scatter via per-block LDS cursors (round-2 style; round-3's global
//    atomic cursors were latency-bound at 165us).
//  - per-(block,bin) offsets from one parallel column-scan kernel
//    (independent coalesced loads, serial only in a register add),
//    replacing round-2's slow totals/fixup pair.
//  - eval brick build in two stages: float4 global->LDS raw staging, then
//    LDS->LDS transpose into z-window layout W4[row][s][c] (float4 = comp c
//    at z=s..s+3). Round-3's build did 4 scalar global loads per window and
//    was VMEM-issue-bound.

#define NBINS 4096  // 16x16x16 bins of 8^3 cells
#define NBLK  256   // hist/scatter blocks (chunked)

__device__ __forceinline__ void bspline_w(float u, float& w0, float& w1,
                                          float& w2, float& w3) {
    const float u2 = u * u;
    const float u3 = u2 * u;
    const float t  = 1.0f - u;
    w0 = t * t * t * (1.0f / 6.0f);
    w1 = (3.0f * u3 - 6.0f * u2 + 4.0f) * (1.0f / 6.0f);
    w2 = (-3.0f * u3 + 3.0f * u2 + 3.0f * u + 1.0f) * (1.0f / 6.0f);
    w3 = u3 * (1.0f / 6.0f);
}

__device__ __forceinline__ int point_bin(float x, float y, float z) {
    const float dx = 2.0f / 125.0f;
    const float ox = -1.0f - dx;
    const int ix = (int)floorf((x - ox - dx) / dx);
    const int iy = (int)floorf((y - ox - dx) / dx);
    const int iz = (int)floorf((z - ox - dx) / dx);
    const int bx = min(max(ix, 0), 127) >> 3;
    const int by = min(max(iy, 0), 127) >> 3;
    const int bz = min(max(iz, 0), 127) >> 3;
    return (bx << 8) | (by << 4) | bz;
}

// ---- pass A: per-block histograms (LDS), coalesced store ----
__global__ __launch_bounds__(256) void hist_kernel(
    const float* __restrict__ xs, const float* __restrict__ ys,
    const float* __restrict__ zs, unsigned* __restrict__ hist,
    int n, int chunk) {
    __shared__ unsigned h[NBINS];
    for (int j = threadIdx.x; j < NBINS; j += 256) h[j] = 0;
    __syncthreads();
    const int b = blockIdx.x;
    const int lo = b * chunk;
    const int hi = min(n, lo + chunk);
    for (int i = lo + threadIdx.x; i < hi; i += 256)
        atomicAdd(&h[point_bin(xs[i], ys[i], zs[i])], 1u);
    __syncthreads();
    for (int j = threadIdx.x; j < NBINS; j += 256) hist[b * NBINS + j] = h[j];
}

// ---- pass B: relative column scan; hist[b][j] -> prefix, total[j] out ----
__global__ __launch_bounds__(256) void colscan_kernel(
    unsigned* __restrict__ hist, unsigned* __restrict__ total) {
    const int j = blockIdx.x * 256 + threadIdx.x;
    unsigned run = 0;
#pragma unroll 8
    for (int b = 0; b < NBLK; ++b) {
        const unsigned c = hist[b * NBINS + j];
        hist[b * NBINS + j] = run;
        run += c;
    }
    total[j] = run;
}

// ---- pass C: exclusive scan of totals -> binbase ----
__global__ __launch_bounds__(1024) void scan_kernel(
    const unsigned* __restrict__ total, unsigned* __restrict__ binbase) {
    __shared__ unsigned sdata[1024];
    const int t = threadIdx.x;
    const unsigned v0 = total[4 * t + 0];
    const unsigned v1 = total[4 * t + 1];
    const unsigned v2 = total[4 * t + 2];
    const unsigned v3 = total[4 * t + 3];
    sdata[t] = v0 + v1 + v2 + v3;
    __syncthreads();
    for (int off = 1; off < 1024; off <<= 1) {
        unsigned x = (t >= off) ? sdata[t - off] : 0u;
        __syncthreads();
        sdata[t] += x;
        __syncthreads();
    }
    const unsigned ex = (t > 0) ? sdata[t - 1] : 0u;
    binbase[4 * t + 0] = ex;
    binbase[4 * t + 1] = ex + v0;
    binbase[4 * t + 2] = ex + v0 + v1;
    binbase[4 * t + 3] = ex + v0 + v1 + v2;
}

// ---- pass D: scatter records, LDS cursors ----
__global__ __launch_bounds__(256) void scatter_kernel(
    const float* __restrict__ xs, const float* __restrict__ ys,
    const float* __restrict__ zs, const unsigned* __restrict__ hist,
    const unsigned* __restrict__ binbase, float4* __restrict__ rec,
    int n, int chunk) {
    __shared__ unsigned off[NBINS];
    const int b = blockIdx.x;
    for (int j = threadIdx.x; j < NBINS; j += 256)
        off[j] = hist[b * NBINS + j] + binbase[j];
    __syncthreads();
    const int lo = b * chunk;
    const int hi = min(n, lo + chunk);
    for (int i = lo + threadIdx.x; i < hi; i += 256) {
        const float x = xs[i], y = ys[i], z = zs[i];
        const unsigned p = atomicAdd(&off[point_bin(x, y, z)], 1u);
        rec[p] = make_float4(x, y, z, __int_as_float(i));
    }
}

// ---- pass E: evaluate, one block per bin ----
// LDS: raw[121][36] floats (z-run staging), W4[121*24] float4 z-windows.
__global__ __launch_bounds__(512) void eval_kernel(
    const float4* __restrict__ rec, const unsigned* __restrict__ binbase,
    const unsigned* __restrict__ total, const float* __restrict__ phi,
    float* __restrict__ out) {
    const int bin = blockIdx.x;
    const unsigned cnt = total[bin];
    if (cnt == 0) return;
    const unsigned start = binbase[bin];

    const int gx0 = ((bin >> 8) & 15) << 3;
    const int gy0 = ((bin >> 4) & 15) << 3;
    const int gz0 = (bin & 15) << 3;

    __shared__ float raw[121 * 36];   // 17424 B
    __shared__ float4 W4[121 * 24];   // 46464 B   (total 63888 B < 64 KB)

    // stage 1: global -> raw. Fast path: 9 float4 per row (z=gz0..gz0+11,
    // no clamp needed when gz0<=112). Slow path only for gz0==120 blocks.
    if (gz0 <= 112) {
        for (int p = threadIdx.x; p < 121 * 9; p += 512) {
            const int row = p / 9;
            const int q   = p - row * 9;
            const int lx = row / 11, ly = row - (row / 11) * 11;
            const int gx = min(gx0 + lx, 127);
            const int gy = min(gy0 + ly, 127);
            const float* src =
                phi + (size_t)((gx * 128 + gy) * 128 + gz0) * 3 + q * 4;
            *reinterpret_cast<float4*>(&raw[row * 36 + q * 4]) =
                *reinterpret_cast<const float4*>(src);
        }
    } else {
        for (int p = threadIdx.x; p < 121 * 11; p += 512) {
            const int row = p / 11;
            const int zz  = p - row * 11;
            const int lx = row / 11, ly = row - (row / 11) * 11;
            const int gx = min(gx0 + lx, 127);
            const int gy = min(gy0 + ly, 127);
            const int z  = min(gz0 + zz, 127);
            const float* s = phi + (size_t)((gx * 128 + gy) * 128 + z) * 3;
            raw[row * 36 + zz * 3 + 0] = s[0];
            raw[row * 36 + zz * 3 + 1] = s[1];
            raw[row * 36 + zz * 3 + 2] = s[2];
        }
    }
    __syncthreads();

    // stage 2: raw -> z-windows. W4[row*24 + s*3 + c] = comp c, z=s..s+3.
    for (int p = threadIdx.x; p < 121 * 24; p += 512) {
        const int row = p / 24;
        const int t   = p - row * 24;  // t = s*3 + c
        const int s   = t / 3;
        const int c   = t - 3 * s;
        const float* r = &raw[row * 36 + s * 3 + c];
        W4[p] = make_float4(r[0], r[3], r[6], r[9]);
    }
    __syncthreads();

    const float dx = 2.0f / 125.0f;
    const float ox = -1.0f - dx;

    for (unsigned k = start + threadIdx.x; k < start + cnt; k += 512) {
        const float4 r4 = rec[k];
        const int idx = __float_as_int(r4.w);

        const float U = (r4.x - ox - dx) / dx;
        const float V = (r4.y - ox - dx) / dx;
        const float Z = (r4.z - ox - dx) / dx;
        const float fu = floorf(U), fv = floorf(V), fw = floorf(Z);
        const int ix = (int)fu, iy = (int)fv, iz = (int)fw;
        const float u = U - fu, v = V - fv, w = Z - fw;

        float wu[4], wv[4], wz[4];
        bspline_w(u, wu[0], wu[1], wu[2], wu[3]);
        bspline_w(v, wv[0], wv[1], wv[2], wv[3]);
        bspline_w(w, wz[0], wz[1], wz[2], wz[3]);

        // z clamp via weight shift
        int izb = iz < 0 ? 0 : iz;
        const bool sh = izb > 124;
        if (sh) izb = 124;
        const float zw0 = sh ? 0.0f : wz[0];
        const float zw1 = sh ? wz[0] : wz[1];
        const float zw2 = sh ? wz[1] : wz[2];
        const float zw3 = sh ? (wz[2] + wz[3]) : wz[3];
        const int lzb3 = (izb - gz0) * 3;  // lzb in [0,7]

        int lxi[4], lyi[4];
#pragma unroll
        for (int l = 0; l < 4; ++l) {
            lxi[l] = min(max(ix + l, 0), 127) - gx0;
            lyi[l] = min(max(iy + l, 0), 127) - gy0;
        }

        float acc0 = 0.0f, acc1 = 0.0f, acc2 = 0.0f;
#pragma unroll
        for (int l = 0; l < 4; ++l) {
            const int rowx = lxi[l] * 11;
#pragma unroll
            for (int m = 0; m < 4; ++m) {
                const int base = (rowx + lyi[m]) * 24 + lzb3;
                const float4 a  = W4[base + 0];
                const float4 bb = W4[base + 1];
                const float4 cc = W4[base + 2];
                const float wm = wu[l] * wv[m];
                const float c0 = wm * zw0;
                const float c1 = wm * zw1;
                const float c2 = wm * zw2;
                const float c3 = wm * zw3;
                acc0 = fmaf(c0, a.x, acc0);
                acc0 = fmaf(c1, a.y, acc0);
                acc0 = fmaf(c2, a.z, acc0);
                acc0 = fmaf(c3, a.w, acc0);
                acc1 = fmaf(c0, bb.x, acc1);
                acc1 = fmaf(c1, bb.y, acc1);
                acc1 = fmaf(c2, bb.z, acc1);
                acc1 = fmaf(c3, bb.w, acc1);
                acc2 = fmaf(c0, cc.x, acc2);
                acc2 = fmaf(c1, cc.y, acc2);
                acc2 = fmaf(c2, cc.z, acc2);
                acc2 = fmaf(c3, cc.w, acc2);
            }
        }
        float* o = out + 3 * (size_t)idx;
        o[0] = acc0;
        o[1] = acc1;
        o[2] = acc2;
    }
}

// ---- fallback: round-1 direct kernel ----
__global__ __launch_bounds__(256) void bspline3d_direct(
    const float* __restrict__ xs, const float* __restrict__ ys,
    const float* __restrict__ zs, const float* __restrict__ phi,
    float* __restrict__ out, int n) {
    const int i = blockIdx.x * blockDim.x + threadIdx.x;
    if (i >= n) return;
    const float dx = 2.0f / 125.0f;
    const float ox = -1.0f - dx;
    float u = (xs[i] - ox - dx) / dx;
    float v = (ys[i] - ox - dx) / dx;
    float w = (zs[i] - ox - dx) / dx;
    const float fu = floorf(u), fv = floorf(v), fw = floorf(w);
    const int ix = (int)fu, iy = (int)fv, iz = (int)fw;
    u -= fu; v -= fv; w -= fw;
    float wu[4], wv[4], wz[4];
    bspline_w(u, wu[0], wu[1], wu[2], wu[3]);
    bspline_w(v, wv[0], wv[1], wv[2], wv[3]);
    bspline_w(w, wz[0], wz[1], wz[2], wz[3]);
    int izb = iz < 0 ? 0 : iz;
    const bool sh = izb > 124;
    if (sh) izb = 124;
    const float zw0 = sh ? 0.0f : wz[0];
    const float zw1 = sh ? wz[0] : wz[1];
    const float zw2 = sh ? wz[1] : wz[2];
    const float zw3 = sh ? (wz[2] + wz[3]) : wz[3];
    int xi[4], yi[4];
#pragma unroll
    for (int l = 0; l < 4; ++l) {
        xi[l] = min(max(ix + l, 0), 127);
        yi[l] = min(max(iy + l, 0), 127);
    }
    const float* pz = phi + izb * 3;
    float acc0 = 0.0f, acc1 = 0.0f, acc2 = 0.0f;
#pragma unroll
    for (int l = 0; l < 4; ++l) {
        const int rowx = xi[l] << 7;
#pragma unroll
        for (int m = 0; m < 4; ++m) {
            const float* p = pz + (rowx + yi[m]) * 384;
            const float4 a = *reinterpret_cast<const float4*>(p);
            const float4 b = *reinterpret_cast<const float4*>(p + 4);
            const float4 c = *reinterpret_cast<const float4*>(p + 8);
            const float wm = wu[l] * wv[m];
            const float c0 = wm * zw0, c1 = wm * zw1, c2 = wm * zw2, c3 = wm * zw3;
            acc0 = fmaf(c0, a.x, acc0); acc1 = fmaf(c0, a.y, acc1); acc2 = fmaf(c0, a.z, acc2);
            acc0 = fmaf(c1, a.w, acc0); acc1 = fmaf(c1, b.x, acc1); acc2 = fmaf(c1, b.y, acc2);
            acc0 = fmaf(c2, b.z, acc0); acc1 = fmaf(c2, b.w, acc1); acc2 = fmaf(c2, c.x, acc2);
            acc0 = fmaf(c3, c.y, acc0); acc1 = fmaf(c3, c.z, acc1); acc2 = fmaf(c3, c.w, acc2);
        }
    }
    float* o = out + 3 * (size_t)i;
    o[0] = acc0; o[1] = acc1; o[2] = acc2;
}

extern "C" void kernel_launch(void* const* d_in, const int* in_sizes, int n_in,
                              void* d_out, int out_size, void* d_ws,
                              size_t ws_size, hipStream_t stream) {
    const float* xs  = (const float*)d_in[0];
    const float* ys  = (const float*)d_in[1];
    const float* zs  = (const float*)d_in[2];
    const float* phi = (const float*)d_in[3];
    float* out = (float*)d_out;
    const int n = in_sizes[0];

    // ws layout
    const size_t hist_off  = 0;                                   // u32[256][4096]
    const size_t total_off = hist_off + (size_t)NBLK * NBINS * 4; // u32[4096]
    const size_t base_off  = total_off + NBINS * 4;               // u32[4096]
    const size_t rec_off   = base_off + NBINS * 4;                // float4[n]
    const size_t need = rec_off + (size_t)n * 16;

    if (ws_size < need) {
        bspline3d_direct<<<(n + 255) / 256, 256, 0, stream>>>(xs, ys, zs, phi,
                                                              out, n);
        return;
    }

    unsigned* hist    = (unsigned*)((char*)d_ws + hist_off);
    unsigned* total   = (unsigned*)((char*)d_ws + total_off);
    unsigned* binbase = (unsigned*)((char*)d_ws + base_off);
    float4*   rec     = (float4*)((char*)d_ws + rec_off);

    const int chunk = (n + NBLK - 1) / NBLK;

    hist_kernel<<<NBLK, 256, 0, stream>>>(xs, ys, zs, hist, n, chunk);
    colscan_kernel<<<NBINS / 256, 256, 0, stream>>>(hist, total);
    scan_kernel<<<1, 1024, 0, stream>>>(total, binbase);
    scatter_kernel<<<NBLK, 256, 0, stream>>>(xs, ys, zs, hist, binbase, rec, n,
                                             chunk);
    eval_kernel<<<NBINS, 512, 0, stream>>>(rec, binbase, total, phi, out);
}

// Round 6
// 194.276 us; speedup vs baseline: 1.7341x; 1.1566x over previous
//
#include <hip/hip_runtime.h>

// B-spline 3D field, 2M points, 128^3 x 3 f32 grid.
// Round 5 (resubmit; previous attempt hit GPU acquisition timeout):
//  - hist/scatter: 1024-thread blocks + float4-vectorized coordinate loads
//    (round 4 ran them at 4 waves/CU with scalar loads -> latency-bound,
//    ~115 us combined).
//  - eval: W4 row stride padded 24 -> 25 float4 (96 words % 32 == 0 meant
//    the row index never touched bank selection -> 8-way aliasing on lzb;
//    53K conflict cycles/CU measured). raw staging shrunk to a 31-row
//    rolling chunk => LDS 52.9 KB => 3 blocks/CU instead of 2.

#define NBINS 4096   // 16x16x16 bins of 8^3 cells
#define NBLK  256    // hist/scatter chunks
#define W4STRIDE 25  // float4 per brick row (padded; 24 used)

__device__ __forceinline__ void bspline_w(float u, float& w0, float& w1,
                                          float& w2, float& w3) {
    const float u2 = u * u;
    const float u3 = u2 * u;
    const float t  = 1.0f - u;
    w0 = t * t * t * (1.0f / 6.0f);
    w1 = (3.0f * u3 - 6.0f * u2 + 4.0f) * (1.0f / 6.0f);
    w2 = (-3.0f * u3 + 3.0f * u2 + 3.0f * u + 1.0f) * (1.0f / 6.0f);
    w3 = u3 * (1.0f / 6.0f);
}

__device__ __forceinline__ int point_bin(float x, float y, float z) {
    const float dx = 2.0f / 125.0f;
    const float ox = -1.0f - dx;
    const int ix = (int)floorf((x - ox - dx) / dx);
    const int iy = (int)floorf((y - ox - dx) / dx);
    const int iz = (int)floorf((z - ox - dx) / dx);
    const int bx = min(max(ix, 0), 127) >> 3;
    const int by = min(max(iy, 0), 127) >> 3;
    const int bz = min(max(iz, 0), 127) >> 3;
    return (bx << 8) | (by << 4) | bz;
}

// ---- pass A: per-block histograms, vectorized ----
__global__ __launch_bounds__(1024) void hist_kernel(
    const float* __restrict__ xs, const float* __restrict__ ys,
    const float* __restrict__ zs, unsigned* __restrict__ hist,
    int n, int chunk) {
    __shared__ unsigned h[NBINS];
    for (int j = threadIdx.x; j < NBINS; j += 1024) h[j] = 0;
    __syncthreads();
    const int b = blockIdx.x;
    const int lo = b * chunk;           // chunk % 4 == 0 -> aligned
    const int hi = min(n, lo + chunk);
    for (int base = lo + threadIdx.x * 4; base < hi; base += 1024 * 4) {
        if (base + 4 <= hi) {
            const float4 x4 = *reinterpret_cast<const float4*>(xs + base);
            const float4 y4 = *reinterpret_cast<const float4*>(ys + base);
            const float4 z4 = *reinterpret_cast<const float4*>(zs + base);
            atomicAdd(&h[point_bin(x4.x, y4.x, z4.x)], 1u);
            atomicAdd(&h[point_bin(x4.y, y4.y, z4.y)], 1u);
            atomicAdd(&h[point_bin(x4.z, y4.z, z4.z)], 1u);
            atomicAdd(&h[point_bin(x4.w, y4.w, z4.w)], 1u);
        } else {
            for (int i = base; i < hi; ++i)
                atomicAdd(&h[point_bin(xs[i], ys[i], zs[i])], 1u);
        }
    }
    __syncthreads();
    for (int j = threadIdx.x; j < NBINS; j += 1024) hist[b * NBINS + j] = h[j];
}

// ---- pass B: relative column scan; hist[b][j] -> prefix, total[j] ----
__global__ __launch_bounds__(256) void colscan_kernel(
    unsigned* __restrict__ hist, unsigned* __restrict__ total) {
    const int j = blockIdx.x * 256 + threadIdx.x;
    unsigned run = 0;
#pragma unroll 16
    for (int b = 0; b < NBLK; ++b) {
        const unsigned c = hist[b * NBINS + j];
        hist[b * NBINS + j] = run;
        run += c;
    }
    total[j] = run;
}

// ---- pass C: exclusive scan of totals -> binbase ----
__global__ __launch_bounds__(1024) void scan_kernel(
    const unsigned* __restrict__ total, unsigned* __restrict__ binbase) {
    __shared__ unsigned sdata[1024];
    const int t = threadIdx.x;
    const unsigned v0 = total[4 * t + 0];
    const unsigned v1 = total[4 * t + 1];
    const unsigned v2 = total[4 * t + 2];
    const unsigned v3 = total[4 * t + 3];
    sdata[t] = v0 + v1 + v2 + v3;
    __syncthreads();
    for (int off = 1; off < 1024; off <<= 1) {
        unsigned x = (t >= off) ? sdata[t - off] : 0u;
        __syncthreads();
        sdata[t] += x;
        __syncthreads();
    }
    const unsigned ex = (t > 0) ? sdata[t - 1] : 0u;
    binbase[4 * t + 0] = ex;
    binbase[4 * t + 1] = ex + v0;
    binbase[4 * t + 2] = ex + v0 + v1;
    binbase[4 * t + 3] = ex + v0 + v1 + v2;
}

// ---- pass D: scatter records, LDS cursors, vectorized ----
__global__ __launch_bounds__(1024) void scatter_kernel(
    const float* __restrict__ xs, const float* __restrict__ ys,
    const float* __restrict__ zs, const unsigned* __restrict__ hist,
    const unsigned* __restrict__ binbase, float4* __restrict__ rec,
    int n, int chunk) {
    __shared__ unsigned off[NBINS];
    const int b = blockIdx.x;
    for (int j = threadIdx.x; j < NBINS; j += 1024)
        off[j] = hist[b * NBINS + j] + binbase[j];
    __syncthreads();
    const int lo = b * chunk;
    const int hi = min(n, lo + chunk);
    for (int base = lo + threadIdx.x * 4; base < hi; base += 1024 * 4) {
        if (base + 4 <= hi) {
            const float4 x4 = *reinterpret_cast<const float4*>(xs + base);
            const float4 y4 = *reinterpret_cast<const float4*>(ys + base);
            const float4 z4 = *reinterpret_cast<const float4*>(zs + base);
            unsigned p;
            p = atomicAdd(&off[point_bin(x4.x, y4.x, z4.x)], 1u);
            rec[p] = make_float4(x4.x, y4.x, z4.x, __int_as_float(base + 0));
            p = atomicAdd(&off[point_bin(x4.y, y4.y, z4.y)], 1u);
            rec[p] = make_float4(x4.y, y4.y, z4.y, __int_as_float(base + 1));
            p = atomicAdd(&off[point_bin(x4.z, y4.z, z4.z)], 1u);
            rec[p] = make_float4(x4.z, y4.z, z4.z, __int_as_float(base + 2));
            p = atomicAdd(&off[point_bin(x4.w, y4.w, z4.w)], 1u);
            rec[p] = make_float4(x4.w, y4.w, z4.w, __int_as_float(base + 3));
        } else {
            for (int i = base; i < hi; ++i) {
                const float x = xs[i], y = ys[i], z = zs[i];
                const unsigned p = atomicAdd(&off[point_bin(x, y, z)], 1u);
                rec[p] = make_float4(x, y, z, __int_as_float(i));
            }
        }
    }
}

// ---- pass E: evaluate, one block per bin ----
__global__ __launch_bounds__(512, 6) void eval_kernel(
    const float4* __restrict__ rec, const unsigned* __restrict__ binbase,
    const unsigned* __restrict__ total, const float* __restrict__ phi,
    float* __restrict__ out) {
    const int bin = blockIdx.x;
    const unsigned cnt = total[bin];
    if (cnt == 0) return;
    const unsigned start = binbase[bin];

    const int gx0 = ((bin >> 8) & 15) << 3;
    const int gy0 = ((bin >> 4) & 15) << 3;
    const int gz0 = (bin & 15) << 3;

    __shared__ float raw[31 * 36];            // 4464 B rolling stage
    __shared__ float4 W4[121 * W4STRIDE];     // 48400 B  (total 52.9 KB)

    // build W4 in 4 row-chunks: global->raw (float4), raw->z-windows.
    for (int r0 = 0; r0 < 121; r0 += 31) {
        const int nr = min(31, 121 - r0);
        if (gz0 <= 112) {
            for (int p = threadIdx.x; p < nr * 9; p += 512) {
                const int rr = p / 9, q = p - rr * 9;
                const int row = r0 + rr;
                const int lx = row / 11, ly = row - lx * 11;
                const int gx = min(gx0 + lx, 127);
                const int gy = min(gy0 + ly, 127);
                const float* src =
                    phi + (size_t)((gx * 128 + gy) * 128 + gz0) * 3 + q * 4;
                *reinterpret_cast<float4*>(&raw[rr * 36 + q * 4]) =
                    *reinterpret_cast<const float4*>(src);
            }
        } else {
            for (int p = threadIdx.x; p < nr * 11; p += 512) {
                const int rr = p / 11, zz = p - rr * 11;
                const int row = r0 + rr;
                const int lx = row / 11, ly = row - lx * 11;
                const int gx = min(gx0 + lx, 127);
                const int gy = min(gy0 + ly, 127);
                const int z  = min(gz0 + zz, 127);
                const float* s = phi + (size_t)((gx * 128 + gy) * 128 + z) * 3;
                raw[rr * 36 + zz * 3 + 0] = s[0];
                raw[rr * 36 + zz * 3 + 1] = s[1];
                raw[rr * 36 + zz * 3 + 2] = s[2];
            }
        }
        __syncthreads();
        for (int p = threadIdx.x; p < nr * 24; p += 512) {
            const int rr = p / 24, t = p - rr * 24;
            const int s = t / 3, c = t - 3 * s;
            const float* r = &raw[rr * 36 + s * 3 + c];
            W4[(r0 + rr) * W4STRIDE + t] = make_float4(r[0], r[3], r[6], r[9]);
        }
        __syncthreads();
    }

    const float dx = 2.0f / 125.0f;
    const float ox = -1.0f - dx;

    for (unsigned k = start + threadIdx.x; k < start + cnt; k += 512) {
        const float4 r4 = rec[k];
        const int idx = __float_as_int(r4.w);

        const float U = (r4.x - ox - dx) / dx;
        const float V = (r4.y - ox - dx) / dx;
        const float Z = (r4.z - ox - dx) / dx;
        const float fu = floorf(U), fv = floorf(V), fw = floorf(Z);
        const int ix = (int)fu, iy = (int)fv, iz = (int)fw;
        const float u = U - fu, v = V - fv, w = Z - fw;

        float wu[4], wv[4], wz[4];
        bspline_w(u, wu[0], wu[1], wu[2], wu[3]);
        bspline_w(v, wv[0], wv[1], wv[2], wv[3]);
        bspline_w(w, wz[0], wz[1], wz[2], wz[3]);

        int izb = iz < 0 ? 0 : iz;
        const bool sh = izb > 124;
        if (sh) izb = 124;
        const float zw0 = sh ? 0.0f : wz[0];
        const float zw1 = sh ? wz[0] : wz[1];
        const float zw2 = sh ? wz[1] : wz[2];
        const float zw3 = sh ? (wz[2] + wz[3]) : wz[3];
        const int lzb3 = (izb - gz0) * 3;

        int lxi[4], lyi[4];
#pragma unroll
        for (int l = 0; l < 4; ++l) {
            lxi[l] = min(max(ix + l, 0), 127) - gx0;
            lyi[l] = min(max(iy + l, 0), 127) - gy0;
        }

        float acc0 = 0.0f, acc1 = 0.0f, acc2 = 0.0f;
#pragma unroll
        for (int l = 0; l < 4; ++l) {
            const int rowx = lxi[l] * 11;
#pragma unroll
            for (int m = 0; m < 4; ++m) {
                const int base = (rowx + lyi[m]) * W4STRIDE + lzb3;
                const float4 a  = W4[base + 0];
                const float4 bb = W4[base + 1];
                const float4 cc = W4[base + 2];
                const float wm = wu[l] * wv[m];
                const float c0 = wm * zw0;
                const float c1 = wm * zw1;
                const float c2 = wm * zw2;
                const float c3 = wm * zw3;
                acc0 = fmaf(c0, a.x, acc0);
                acc0 = fmaf(c1, a.y, acc0);
                acc0 = fmaf(c2, a.z, acc0);
                acc0 = fmaf(c3, a.w, acc0);
                acc1 = fmaf(c0, bb.x, acc1);
                acc1 = fmaf(c1, bb.y, acc1);
                acc1 = fmaf(c2, bb.z, acc1);
                acc1 = fmaf(c3, bb.w, acc1);
                acc2 = fmaf(c0, cc.x, acc2);
                acc2 = fmaf(c1, cc.y, acc2);
                acc2 = fmaf(c2, cc.z, acc2);
                acc2 = fmaf(c3, cc.w, acc2);
            }
        }
        float* o = out + 3 * (size_t)idx;
        o[0] = acc0;
        o[1] = acc1;
        o[2] = acc2;
    }
}

// ---- fallback: round-1 direct kernel ----
__global__ __launch_bounds__(256) void bspline3d_direct(
    const float* __restrict__ xs, const float* __restrict__ ys,
    const float* __restrict__ zs, const float* __restrict__ phi,
    float* __restrict__ out, int n) {
    const int i = blockIdx.x * blockDim.x + threadIdx.x;
    if (i >= n) return;
    const float dx = 2.0f / 125.0f;
    const float ox = -1.0f - dx;
    float u = (xs[i] - ox - dx) / dx;
    float v = (ys[i] - ox - dx) / dx;
    float w = (zs[i] - ox - dx) / dx;
    const float fu = floorf(u), fv = floorf(v), fw = floorf(w);
    const int ix = (int)fu, iy = (int)fv, iz = (int)fw;
    u -= fu; v -= fv; w -= fw;
    float wu[4], wv[4], wz[4];
    bspline_w(u, wu[0], wu[1], wu[2], wu[3]);
    bspline_w(v, wv[0], wv[1], wv[2], wv[3]);
    bspline_w(w, wz[0], wz[1], wz[2], wz[3]);
    int izb = iz < 0 ? 0 : iz;
    const bool sh = izb > 124;
    if (sh) izb = 124;
    const float zw0 = sh ? 0.0f : wz[0];
    const float zw1 = sh ? wz[0] : wz[1];
    const float zw2 = sh ? wz[1] : wz[2];
    const float zw3 = sh ? (wz[2] + wz[3]) : wz[3];
    int xi[4], yi[4];
#pragma unroll
    for (int l = 0; l < 4; ++l) {
        xi[l] = min(max(ix + l, 0), 127);
        yi[l] = min(max(iy + l, 0), 127);
    }
    const float* pz = phi + izb * 3;
    float acc0 = 0.0f, acc1 = 0.0f, acc2 = 0.0f;
#pragma unroll
    for (int l = 0; l < 4; ++l) {
        const int rowx = xi[l] << 7;
#pragma unroll
        for (int m = 0; m < 4; ++m) {
            const float* p = pz + (rowx + yi[m]) * 384;
            const float4 a = *reinterpret_cast<const float4*>(p);
            const float4 b = *reinterpret_cast<const float4*>(p + 4);
            const float4 c = *reinterpret_cast<const float4*>(p + 8);
            const float wm = wu[l] * wv[m];
            const float c0 = wm * zw0, c1 = wm * zw1, c2 = wm * zw2, c3 = wm * zw3;
            acc0 = fmaf(c0, a.x, acc0); acc1 = fmaf(c0, a.y, acc1); acc2 = fmaf(c0, a.z, acc2);
            acc0 = fmaf(c1, a.w, acc0); acc1 = fmaf(c1, b.x, acc1); acc2 = fmaf(c1, b.y, acc2);
            acc0 = fmaf(c2, b.z, acc0); acc1 = fmaf(c2, b.w, acc1); acc2 = fmaf(c2, c.x, acc2);
            acc0 = fmaf(c3, c.y, acc0); acc1 = fmaf(c3, c.z, acc1); acc2 = fmaf(c3, c.w, acc2);
        }
    }
    float* o = out + 3 * (size_t)i;
    o[0] = acc0; o[1] = acc1; o[2] = acc2;
}

extern "C" void kernel_launch(void* const* d_in, const int* in_sizes, int n_in,
                              void* d_out, int out_size, void* d_ws,
                              size_t ws_size, hipStream_t stream) {
    const float* xs  = (const float*)d_in[0];
    const float* ys  = (const float*)d_in[1];
    const float* zs  = (const float*)d_in[2];
    const float* phi = (const float*)d_in[3];
    float* out = (float*)d_out;
    const int n = in_sizes[0];

    const size_t hist_off  = 0;                                    // u32[256][4096]
    const size_t total_off = hist_off + (size_t)NBLK * NBINS * 4;  // u32[4096]
    const size_t base_off  = total_off + NBINS * 4;                // u32[4096]
    const size_t rec_off   = base_off + NBINS * 4;                 // float4[n]
    const size_t need = rec_off + (size_t)n * 16;

    if (ws_size < need) {
        bspline3d_direct<<<(n + 255) / 256, 256, 0, stream>>>(xs, ys, zs, phi,
                                                              out, n);
        return;
    }

    unsigned* hist    = (unsigned*)((char*)d_ws + hist_off);
    unsigned* total   = (unsigned*)((char*)d_ws + total_off);
    unsigned* binbase = (unsigned*)((char*)d_ws + base_off);
    float4*   rec     = (float4*)((char*)d_ws + rec_off);

    // chunk multiple of 4 so vectorized loads stay 16B-aligned
    const int chunk = (((n + NBLK - 1) / NBLK) + 3) & ~3;

    hist_kernel<<<NBLK, 1024, 0, stream>>>(xs, ys, zs, hist, n, chunk);
    colscan_kernel<<<NBINS / 256, 256, 0, stream>>>(hist, total);
    scan_kernel<<<1, 1024, 0, stream>>>(total, binbase);
    scatter_kernel<<<NBLK, 1024, 0, stream>>>(xs, ys, zs, hist, binbase, rec,
                                              n, chunk);
    eval_kernel<<<NBINS, 512, 0, stream>>>(rec, binbase, total, phi, out);
}